// Round 1
// baseline (4632.320 us; speedup 1.0000x reference)
//
#include <hip/hip_runtime.h>

#define N_NODES 100000
#define N_EDGES 3200000

// ---------------- edge scatter kernels ----------------

// Layer 1: 32 channels. One thread per (edge, float4 quad of 8). Also counts degree.
__global__ __launch_bounds__(256) void scatter1(
    const int* __restrict__ src, const int* __restrict__ tgt,
    const float* __restrict__ x, float* __restrict__ agg, float* __restrict__ deg) {
  int tid = blockIdx.x * blockDim.x + threadIdx.x;
  if (tid >= N_EDGES * 8) return;
  int e = tid >> 3, q = tid & 7;
  int s = src[e], t = tgt[e];
  float4 v = reinterpret_cast<const float4*>(x)[s * 8 + q];
  float* a = agg + t * 32 + q * 4;
  atomicAdd(a + 0, v.x);
  atomicAdd(a + 1, v.y);
  atomicAdd(a + 2, v.z);
  atomicAdd(a + 3, v.w);
  if (q == 0) atomicAdd(deg + t, 1.0f);
}

// Layer 2: 64 channels. One thread per (edge, float4 quad of 16).
__global__ __launch_bounds__(256) void scatter2(
    const int* __restrict__ src, const int* __restrict__ tgt,
    const float* __restrict__ h, float* __restrict__ agg) {
  int tid = blockIdx.x * blockDim.x + threadIdx.x;
  if (tid >= N_EDGES * 16) return;
  int e = tid >> 4, q = tid & 15;
  int s = src[e], t = tgt[e];
  float4 v = reinterpret_cast<const float4*>(h)[s * 16 + q];
  float* a = agg + t * 64 + q * 4;
  atomicAdd(a + 0, v.x);
  atomicAdd(a + 1, v.y);
  atomicAdd(a + 2, v.z);
  atomicAdd(a + 3, v.w);
}

// Layer 3: 2 channels (post-multiplied by W_l3). Scales by inv-degree of target.
__global__ __launch_bounds__(256) void scatter3(
    const int* __restrict__ src, const int* __restrict__ tgt,
    const float* __restrict__ y, const float* __restrict__ invdeg,
    float* __restrict__ out) {
  int e = blockIdx.x * blockDim.x + threadIdx.x;
  if (e >= N_EDGES) return;
  int s = src[e], t = tgt[e];
  float2 v = reinterpret_cast<const float2*>(y)[s];
  float inv = invdeg[t];
  atomicAdd(out + t * 2 + 0, v.x * inv);
  atomicAdd(out + t * 2 + 1, v.y * inv);
}

// ---------------- node-level kernels ----------------

// One wave (64 lanes) per node; lane c = output channel.
// h[c] = sum_k (agg[k]*inv) * Wl[k][c] + sum_k xin[k] * Wr[k][c] + b[c]
// then LayerNorm over the 64 channels (wave shfl reduce) + ReLU.
// LAYER1: deg holds raw degree -> computes inv, writes it back in place.
template <int CIN, int LAYER1>
__global__ __launch_bounds__(256) void node_ln(
    const float* __restrict__ xin, const float* __restrict__ agg,
    float* __restrict__ deg,  // raw degree (layer1) or inv-degree (layer2)
    const float* __restrict__ Wl, const float* __restrict__ Wr,
    const float* __restrict__ b, const float* __restrict__ g,
    const float* __restrict__ be, float* __restrict__ hout) {
  int gid = blockIdx.x * blockDim.x + threadIdx.x;
  int node = gid >> 6;
  int c = threadIdx.x & 63;
  if (node >= N_NODES) return;

  float inv;
  if (LAYER1) {
    float dg = deg[node];
    inv = 1.0f / fmaxf(dg, 1.0f);
    if (c == 0) deg[node] = inv;  // all lanes loaded before lane0 stores (wave lockstep)
  } else {
    inv = deg[node];
  }

  const float* xr = xin + node * CIN;
  const float* ar = agg + node * CIN;
  float acc = b[c];
#pragma unroll
  for (int k = 0; k < CIN; k++) {
    acc = fmaf(ar[k] * inv, Wl[k * 64 + c], acc);
    acc = fmaf(xr[k], Wr[k * 64 + c], acc);
  }

  // LayerNorm across 64 lanes
  float s = acc;
#pragma unroll
  for (int off = 32; off; off >>= 1) s += __shfl_xor(s, off);
  float mu = s * (1.0f / 64.0f);
  float d = acc - mu;
  float v2 = d * d;
#pragma unroll
  for (int off = 32; off; off >>= 1) v2 += __shfl_xor(v2, off);
  float var = v2 * (1.0f / 64.0f);
  float o = d * rsqrtf(var + 1e-5f) * g[c] + be[c];
  hout[node * 64 + c] = fmaxf(o, 0.0f);
}

// Per node: y = h2 @ W_l3 (staged for scatter3), out = h2 @ W_r3 + b3 (self term).
__global__ __launch_bounds__(256) void node3(
    const float* __restrict__ h, const float* __restrict__ Wl,
    const float* __restrict__ Wr, const float* __restrict__ b,
    float* __restrict__ y, float* __restrict__ out) {
  int i = blockIdx.x * blockDim.x + threadIdx.x;
  if (i >= N_NODES) return;
  const float* hr = h + i * 64;
  float y0 = 0.f, y1 = 0.f, r0 = b[0], r1 = b[1];
#pragma unroll
  for (int k = 0; k < 64; k++) {
    float hv = hr[k];
    y0 = fmaf(hv, Wl[k * 2 + 0], y0);
    y1 = fmaf(hv, Wl[k * 2 + 1], y1);
    r0 = fmaf(hv, Wr[k * 2 + 0], r0);
    r1 = fmaf(hv, Wr[k * 2 + 1], r1);
  }
  reinterpret_cast<float2*>(y)[i] = make_float2(y0, y1);
  reinterpret_cast<float2*>(out)[i] = make_float2(r0, r1);
}

// ---------------- launch ----------------

extern "C" void kernel_launch(void* const* d_in, const int* in_sizes, int n_in,
                              void* d_out, int out_size, void* d_ws, size_t ws_size,
                              hipStream_t stream) {
  const float* x = (const float*)d_in[0];
  const int* ei = (const int*)d_in[1];
  const int* src = ei;
  const int* tgt = ei + N_EDGES;
  const float* Wl1 = (const float*)d_in[2];
  const float* Wr1 = (const float*)d_in[3];
  const float* b1 = (const float*)d_in[4];
  const float* g1 = (const float*)d_in[5];
  const float* be1 = (const float*)d_in[6];
  const float* Wl2 = (const float*)d_in[7];
  const float* Wr2 = (const float*)d_in[8];
  const float* b2 = (const float*)d_in[9];
  const float* g2 = (const float*)d_in[10];
  const float* be2 = (const float*)d_in[11];
  const float* Wl3 = (const float*)d_in[12];
  const float* Wr3 = (const float*)d_in[13];
  const float* b3 = (const float*)d_in[14];
  float* out = (float*)d_out;

  // workspace layout
  char* ws = (char*)d_ws;
  float* deg = (float*)ws;                       // N floats (deg -> invdeg in place)
  float* A = (float*)(ws + (size_t)N_NODES * 4); // N*64 floats: agg1/agg2, then y3
  float* B = A + (size_t)N_NODES * 64;           // N*64 floats: h1, then h2 in place

  // ---- layer 1 ----
  hipMemsetAsync(deg, 0, (size_t)N_NODES * 4, stream);
  hipMemsetAsync(A, 0, (size_t)N_NODES * 32 * 4, stream);
  scatter1<<<(N_EDGES * 8 + 255) / 256, 256, 0, stream>>>(src, tgt, x, A, deg);
  node_ln<32, 1><<<(N_NODES * 64 + 255) / 256, 256, 0, stream>>>(
      x, A, deg, Wl1, Wr1, b1, g1, be1, B);

  // ---- layer 2 ----
  hipMemsetAsync(A, 0, (size_t)N_NODES * 64 * 4, stream);
  scatter2<<<(N_EDGES * 16 + 255) / 256, 256, 0, stream>>>(src, tgt, B, A);
  node_ln<64, 0><<<(N_NODES * 64 + 255) / 256, 256, 0, stream>>>(
      B, A, deg, Wl2, Wr2, b2, g2, be2, B);  // h2 overwrites h1 in place (row-local)

  // ---- layer 3 (aggregate post-multiplied 2-ch features) ----
  float* y3 = A;  // reuse agg buffer
  node3<<<(N_NODES + 255) / 256, 256, 0, stream>>>(B, Wl3, Wr3, b3, y3, out);
  scatter3<<<(N_EDGES + 255) / 256, 256, 0, stream>>>(src, tgt, y3, deg, out);
}

// Round 2
// 813.591 us; speedup vs baseline: 5.6937x; 5.6937x over previous
//
#include <hip/hip_runtime.h>

#define N_NODES 100000
#define N_EDGES 3200000

// ==================== common helpers ====================

__device__ __forceinline__ int wave_incl_scan_i(int v) {
  int lane = threadIdx.x & 63;
#pragma unroll
  for (int off = 1; off < 64; off <<= 1) {
    int n = __shfl_up(v, off);
    if (lane >= off) v += n;
  }
  return v;
}

// ==================== CSR build ====================

__global__ __launch_bounds__(256) void k_count(const int* __restrict__ tgt,
                                               int* __restrict__ counts) {
  int e = blockIdx.x * 256 + threadIdx.x;
  if (e >= N_EDGES) return;
  atomicAdd(&counts[tgt[e]], 1);
}

// block-wise exclusive scan of counts -> offs (partial), blockSums[b] = block total
__global__ __launch_bounds__(256) void k_scanA(const int* __restrict__ counts,
                                               int* __restrict__ offs,
                                               int* __restrict__ blockSums) {
  __shared__ int lds[4];
  int t = threadIdx.x;
  int gid = blockIdx.x * 256 + t;
  int v = (gid < N_NODES) ? counts[gid] : 0;
  int inc = wave_incl_scan_i(v);
  int lane = t & 63, wid = t >> 6;
  if (lane == 63) lds[wid] = inc;
  __syncthreads();
  if (t == 0) {
    int run = 0;
#pragma unroll
    for (int i = 0; i < 4; i++) { int c = lds[i]; lds[i] = run; run += c; }
    blockSums[blockIdx.x] = run;
  }
  __syncthreads();
  int ex = inc - v + lds[wid];
  if (gid < N_NODES) offs[gid] = ex;
}

// single-block scan of block sums (nb <= 512)
__global__ __launch_bounds__(512) void k_scanB(int* __restrict__ blockSums, int nb) {
  __shared__ int lds[8];
  int t = threadIdx.x;
  int v = (t < nb) ? blockSums[t] : 0;
  int inc = wave_incl_scan_i(v);
  int lane = t & 63, wid = t >> 6;
  if (lane == 63) lds[wid] = inc;
  __syncthreads();
  if (t == 0) {
    int run = 0;
#pragma unroll
    for (int i = 0; i < 8; i++) { int c = lds[i]; lds[i] = run; run += c; }
  }
  __syncthreads();
  int ex = inc - v + lds[wid];
  if (t < nb) blockSums[t] = ex;
}

__global__ __launch_bounds__(256) void k_scanC(int* __restrict__ offs,
                                               const int* __restrict__ blockSums) {
  int gid = blockIdx.x * 256 + threadIdx.x;
  if (gid < N_NODES) offs[gid] += blockSums[blockIdx.x];
}

// fill csr; afterwards offs[t] == row end, row start = (t ? offs[t-1] : 0)
__global__ __launch_bounds__(256) void k_fill(const int* __restrict__ src,
                                              const int* __restrict__ tgt,
                                              int* __restrict__ offs,
                                              int* __restrict__ csr) {
  int e = blockIdx.x * 256 + threadIdx.x;
  if (e >= N_EDGES) return;
  int t = tgt[e];
  int pos = atomicAdd(&offs[t], 1);
  csr[pos] = src[e];
}

// ==================== fused layers (CSR path) ====================

// Layer 1: wave per node. Gather-mean x (32ch, 2 edges/iter) -> 32x64 matmul
// (Wl on agg, Wr on self) -> LayerNorm(64) -> ReLU -> h1.
__global__ __launch_bounds__(256) void layer1_fused(
    const float* __restrict__ x, const int* __restrict__ csr,
    const int* __restrict__ offs, const float* __restrict__ Wl,
    const float* __restrict__ Wr, const float* __restrict__ b,
    const float* __restrict__ g, const float* __restrict__ be,
    float* __restrict__ h1) {
  int node = blockIdx.x * 4 + (threadIdx.x >> 6);
  if (node >= N_NODES) return;
  int lane = threadIdx.x & 63;
  int c = lane & 31, half = lane >> 5;

  int end = offs[node];
  int start = node ? offs[node - 1] : 0;
  float inv = 1.0f / fmaxf((float)(end - start), 1.0f);

  float acc = 0.0f;
  for (int slot = start + half; slot < end; slot += 2)
    acc += x[(size_t)csr[slot] * 32 + c];
  acc += __shfl_xor(acc, 32);  // lane holds agg[lane&31] (dup across halves)

  float xself = x[(size_t)node * 32 + c];
  int o = lane;
  float accO = b[o];
#pragma unroll
  for (int k = 0; k < 32; k++) {
    float ak = __shfl(acc, k);
    float xk = __shfl(xself, k);
    accO = fmaf(ak * inv, Wl[k * 64 + o], accO);
    accO = fmaf(xk, Wr[k * 64 + o], accO);
  }

  // LayerNorm over 64 lanes + ReLU
  float s = accO;
#pragma unroll
  for (int off = 32; off; off >>= 1) s += __shfl_xor(s, off);
  float mu = s * (1.0f / 64.0f);
  float d = accO - mu;
  float v2 = d * d;
#pragma unroll
  for (int off = 32; off; off >>= 1) v2 += __shfl_xor(v2, off);
  float o2 = d * rsqrtf(v2 * (1.0f / 64.0f) + 1e-5f) * g[o] + be[o];
  h1[(size_t)node * 64 + o] = fmaxf(o2, 0.0f);
}

// Layer 2: wave per node. Gather-mean h1 (64ch) -> 64x64 matmul -> LN -> ReLU -> h2.
__global__ __launch_bounds__(256) void layer2_fused(
    const float* __restrict__ h1, const int* __restrict__ csr,
    const int* __restrict__ offs, const float* __restrict__ Wl,
    const float* __restrict__ Wr, const float* __restrict__ b,
    const float* __restrict__ g, const float* __restrict__ be,
    float* __restrict__ h2) {
  int node = blockIdx.x * 4 + (threadIdx.x >> 6);
  if (node >= N_NODES) return;
  int lane = threadIdx.x & 63;

  int end = offs[node];
  int start = node ? offs[node - 1] : 0;
  float inv = 1.0f / fmaxf((float)(end - start), 1.0f);

  float a0 = 0.0f, a1 = 0.0f;
  int slot = start;
  for (; slot + 2 <= end; slot += 2) {
    int s0 = csr[slot], s1 = csr[slot + 1];
    a0 += h1[(size_t)s0 * 64 + lane];
    a1 += h1[(size_t)s1 * 64 + lane];
  }
  if (slot < end) a0 += h1[(size_t)csr[slot] * 64 + lane];
  float agg = a0 + a1;

  float hself = h1[(size_t)node * 64 + lane];
  int o = lane;
  float accO = b[o];
#pragma unroll
  for (int k = 0; k < 64; k++) {
    float ak = __shfl(agg, k);
    float hk = __shfl(hself, k);
    accO = fmaf(ak * inv, Wl[k * 64 + o], accO);
    accO = fmaf(hk, Wr[k * 64 + o], accO);
  }

  float s = accO;
#pragma unroll
  for (int off = 32; off; off >>= 1) s += __shfl_xor(s, off);
  float mu = s * (1.0f / 64.0f);
  float d = accO - mu;
  float v2 = d * d;
#pragma unroll
  for (int off = 32; off; off >>= 1) v2 += __shfl_xor(v2, off);
  float o2 = d * rsqrtf(v2 * (1.0f / 64.0f) + 1e-5f) * g[o] + be[o];
  h2[(size_t)node * 64 + o] = fmaxf(o2, 0.0f);
}

// Layer 3 node part: y = h2 @ W_l3 (staged), out = h2 @ W_r3 + b3 (self term).
__global__ __launch_bounds__(256) void node3(
    const float* __restrict__ h, const float* __restrict__ Wl,
    const float* __restrict__ Wr, const float* __restrict__ b,
    float* __restrict__ y, float* __restrict__ out) {
  int i = blockIdx.x * 256 + threadIdx.x;
  if (i >= N_NODES) return;
  const float* hr = h + (size_t)i * 64;
  float y0 = 0.f, y1 = 0.f, r0 = b[0], r1 = b[1];
#pragma unroll
  for (int k = 0; k < 64; k++) {
    float hv = hr[k];
    y0 = fmaf(hv, Wl[k * 2 + 0], y0);
    y1 = fmaf(hv, Wl[k * 2 + 1], y1);
    r0 = fmaf(hv, Wr[k * 2 + 0], r0);
    r1 = fmaf(hv, Wr[k * 2 + 1], r1);
  }
  reinterpret_cast<float2*>(y)[i] = make_float2(y0, y1);
  reinterpret_cast<float2*>(out)[i] = make_float2(r0, r1);
}

// Layer 3 gather: wave per node, edges strided across lanes, shfl reduce.
__global__ __launch_bounds__(256) void gather3(
    const float* __restrict__ y, const int* __restrict__ csr,
    const int* __restrict__ offs, float* __restrict__ out) {
  int node = blockIdx.x * 4 + (threadIdx.x >> 6);
  if (node >= N_NODES) return;
  int lane = threadIdx.x & 63;

  int end = offs[node];
  int start = node ? offs[node - 1] : 0;
  float inv = 1.0f / fmaxf((float)(end - start), 1.0f);

  float s0 = 0.f, s1 = 0.f;
  for (int slot = start + lane; slot < end; slot += 64) {
    float2 v = reinterpret_cast<const float2*>(y)[csr[slot]];
    s0 += v.x;
    s1 += v.y;
  }
#pragma unroll
  for (int off = 32; off; off >>= 1) {
    s0 += __shfl_xor(s0, off);
    s1 += __shfl_xor(s1, off);
  }
  if (lane == 0) {
    out[(size_t)node * 2 + 0] += s0 * inv;
    out[(size_t)node * 2 + 1] += s1 * inv;
  }
}

// ==================== fallback atomic path (round-1, fits 51.7MB ws) ====================

__global__ __launch_bounds__(256) void scatter1(
    const int* __restrict__ src, const int* __restrict__ tgt,
    const float* __restrict__ x, float* __restrict__ agg, float* __restrict__ deg) {
  int tid = blockIdx.x * blockDim.x + threadIdx.x;
  if (tid >= N_EDGES * 8) return;
  int e = tid >> 3, q = tid & 7;
  int s = src[e], t = tgt[e];
  float4 v = reinterpret_cast<const float4*>(x)[s * 8 + q];
  float* a = agg + t * 32 + q * 4;
  atomicAdd(a + 0, v.x);
  atomicAdd(a + 1, v.y);
  atomicAdd(a + 2, v.z);
  atomicAdd(a + 3, v.w);
  if (q == 0) atomicAdd(deg + t, 1.0f);
}

__global__ __launch_bounds__(256) void scatter2(
    const int* __restrict__ src, const int* __restrict__ tgt,
    const float* __restrict__ h, float* __restrict__ agg) {
  int tid = blockIdx.x * blockDim.x + threadIdx.x;
  if (tid >= N_EDGES * 16) return;
  int e = tid >> 4, q = tid & 15;
  int s = src[e], t = tgt[e];
  float4 v = reinterpret_cast<const float4*>(h)[s * 16 + q];
  float* a = agg + t * 64 + q * 4;
  atomicAdd(a + 0, v.x);
  atomicAdd(a + 1, v.y);
  atomicAdd(a + 2, v.z);
  atomicAdd(a + 3, v.w);
}

__global__ __launch_bounds__(256) void scatter3(
    const int* __restrict__ src, const int* __restrict__ tgt,
    const float* __restrict__ y, const float* __restrict__ invdeg,
    float* __restrict__ out) {
  int e = blockIdx.x * blockDim.x + threadIdx.x;
  if (e >= N_EDGES) return;
  int s = src[e], t = tgt[e];
  float2 v = reinterpret_cast<const float2*>(y)[s];
  float inv = invdeg[t];
  atomicAdd(out + t * 2 + 0, v.x * inv);
  atomicAdd(out + t * 2 + 1, v.y * inv);
}

template <int CIN, int LAYER1>
__global__ __launch_bounds__(256) void node_ln(
    const float* __restrict__ xin, const float* __restrict__ agg,
    float* __restrict__ deg, const float* __restrict__ Wl,
    const float* __restrict__ Wr, const float* __restrict__ b,
    const float* __restrict__ g, const float* __restrict__ be,
    float* __restrict__ hout) {
  int gid = blockIdx.x * blockDim.x + threadIdx.x;
  int node = gid >> 6;
  int c = threadIdx.x & 63;
  if (node >= N_NODES) return;

  float inv;
  if (LAYER1) {
    float dg = deg[node];
    inv = 1.0f / fmaxf(dg, 1.0f);
    if (c == 0) deg[node] = inv;
  } else {
    inv = deg[node];
  }

  const float* xr = xin + (size_t)node * CIN;
  const float* ar = agg + (size_t)node * CIN;
  float acc = b[c];
#pragma unroll
  for (int k = 0; k < CIN; k++) {
    acc = fmaf(ar[k] * inv, Wl[k * 64 + c], acc);
    acc = fmaf(xr[k], Wr[k * 64 + c], acc);
  }

  float s = acc;
#pragma unroll
  for (int off = 32; off; off >>= 1) s += __shfl_xor(s, off);
  float mu = s * (1.0f / 64.0f);
  float d = acc - mu;
  float v2 = d * d;
#pragma unroll
  for (int off = 32; off; off >>= 1) v2 += __shfl_xor(v2, off);
  float var = v2 * (1.0f / 64.0f);
  float o = d * rsqrtf(var + 1e-5f) * g[c] + be[c];
  hout[(size_t)node * 64 + c] = fmaxf(o, 0.0f);
}

// ==================== launch ====================

extern "C" void kernel_launch(void* const* d_in, const int* in_sizes, int n_in,
                              void* d_out, int out_size, void* d_ws, size_t ws_size,
                              hipStream_t stream) {
  const float* x = (const float*)d_in[0];
  const int* ei = (const int*)d_in[1];
  const int* src = ei;
  const int* tgt = ei + N_EDGES;
  const float* Wl1 = (const float*)d_in[2];
  const float* Wr1 = (const float*)d_in[3];
  const float* b1 = (const float*)d_in[4];
  const float* g1 = (const float*)d_in[5];
  const float* be1 = (const float*)d_in[6];
  const float* Wl2 = (const float*)d_in[7];
  const float* Wr2 = (const float*)d_in[8];
  const float* b2 = (const float*)d_in[9];
  const float* g2 = (const float*)d_in[10];
  const float* be2 = (const float*)d_in[11];
  const float* Wl3 = (const float*)d_in[12];
  const float* Wr3 = (const float*)d_in[13];
  const float* b3 = (const float*)d_in[14];
  float* out = (float*)d_out;
  char* ws = (char*)d_ws;

  // ---- CSR-path workspace layout ----
  size_t p = 0;
  auto carve = [&](size_t bytes) {
    size_t r = p;
    p += (bytes + 255) & ~(size_t)255;
    return r;
  };
  size_t counts_off = carve((size_t)N_NODES * 4);
  size_t offs_off = carve((size_t)N_NODES * 4);
  size_t bsums_off = carve(512 * 4);
  size_t csr_off = carve((size_t)N_EDGES * 4);
  size_t B_off = carve((size_t)N_NODES * 64 * 4);  // h1, later y3
  size_t A_off = carve((size_t)N_NODES * 64 * 4);  // h2
  size_t need_csr = p;

  const int NB = (N_NODES + 255) / 256;  // 391

  if (ws_size >= need_csr) {
    int* counts = (int*)(ws + counts_off);
    int* offs = (int*)(ws + offs_off);
    int* bsums = (int*)(ws + bsums_off);
    int* csr = (int*)(ws + csr_off);
    float* B = (float*)(ws + B_off);
    float* A = (float*)(ws + A_off);

    hipMemsetAsync(counts, 0, (size_t)N_NODES * 4, stream);
    k_count<<<(N_EDGES + 255) / 256, 256, 0, stream>>>(tgt, counts);
    k_scanA<<<NB, 256, 0, stream>>>(counts, offs, bsums);
    k_scanB<<<1, 512, 0, stream>>>(bsums, NB);
    k_scanC<<<NB, 256, 0, stream>>>(offs, bsums);
    k_fill<<<(N_EDGES + 255) / 256, 256, 0, stream>>>(src, tgt, offs, csr);

    layer1_fused<<<(N_NODES + 3) / 4, 256, 0, stream>>>(
        x, csr, offs, Wl1, Wr1, b1, g1, be1, B);
    layer2_fused<<<(N_NODES + 3) / 4, 256, 0, stream>>>(
        B, csr, offs, Wl2, Wr2, b2, g2, be2, A);
    float* y3 = B;  // h1 dead; reuse
    node3<<<NB, 256, 0, stream>>>(A, Wl3, Wr3, b3, y3, out);
    gather3<<<(N_NODES + 3) / 4, 256, 0, stream>>>(y3, csr, offs, out);
  } else {
    // fallback: round-1 atomic path (needs ~51.7MB)
    float* deg = (float*)ws;
    float* A = (float*)(ws + (size_t)N_NODES * 4);
    float* B = A + (size_t)N_NODES * 64;

    hipMemsetAsync(deg, 0, (size_t)N_NODES * 4, stream);
    hipMemsetAsync(A, 0, (size_t)N_NODES * 32 * 4, stream);
    scatter1<<<(N_EDGES * 8 + 255) / 256, 256, 0, stream>>>(src, tgt, x, A, deg);
    node_ln<32, 1><<<(N_NODES * 64 + 255) / 256, 256, 0, stream>>>(
        x, A, deg, Wl1, Wr1, b1, g1, be1, B);
    hipMemsetAsync(A, 0, (size_t)N_NODES * 64 * 4, stream);
    scatter2<<<(N_EDGES * 16 + 255) / 256, 256, 0, stream>>>(src, tgt, B, A);
    node_ln<64, 0><<<(N_NODES * 64 + 255) / 256, 256, 0, stream>>>(
        B, A, deg, Wl2, Wr2, b2, g2, be2, B);
    float* y3 = A;
    node3<<<NB, 256, 0, stream>>>(B, Wl3, Wr3, b3, y3, out);
    scatter3<<<(N_EDGES + 255) / 256, 256, 0, stream>>>(src, tgt, y3, deg, out);
  }
}

// Round 3
// 505.915 us; speedup vs baseline: 9.1563x; 1.6082x over previous
//
#include <hip/hip_runtime.h>

#define N_NODES 100000
#define N_EDGES 3200000
#define NBK 391          // ceil(N_NODES / 256) buckets, 256 nodes each
#define EPB 8192         // edges per block in binning passes
#define NBLK_BIN 391     // ceil(N_EDGES / EPB)

// ==================== common helpers ====================

__device__ __forceinline__ int wave_incl_scan_i(int v) {
  int lane = threadIdx.x & 63;
#pragma unroll
  for (int off = 1; off < 64; off <<= 1) {
    int n = __shfl_up(v, off);
    if (lane >= off) v += n;
  }
  return v;
}

// ==================== CSR build: bucketed counting sort ====================

// Pass A: per-bucket edge counts (LDS histogram -> global merge).
__global__ __launch_bounds__(256) void bin_hist(const int* __restrict__ tgt,
                                                int* __restrict__ count) {
  __shared__ int hist[NBK];
  int t = threadIdx.x;
  for (int i = t; i < NBK; i += 256) hist[i] = 0;
  __syncthreads();
  int e0 = blockIdx.x * EPB;
  int e1 = min(e0 + EPB, N_EDGES);
  for (int e = e0 + t; e < e1; e += 256) atomicAdd(&hist[tgt[e] >> 8], 1);
  __syncthreads();
  for (int i = t; i < NBK; i += 256) {
    int c = hist[i];
    if (c) atomicAdd(&count[i], c);
  }
}

// Pass S: exclusive scan of 391 bucket counts -> bktBase, cursor. One block.
__global__ __launch_bounds__(512) void bin_scan(const int* __restrict__ count,
                                                int* __restrict__ bktBase,
                                                int* __restrict__ cursor) {
  __shared__ int lds[8];
  int t = threadIdx.x;
  int v = (t < NBK) ? count[t] : 0;
  int inc = wave_incl_scan_i(v);
  int lane = t & 63, wid = t >> 6;
  if (lane == 63) lds[wid] = inc;
  __syncthreads();
  if (t == 0) {
    int run = 0;
#pragma unroll
    for (int i = 0; i < 8; i++) { int c = lds[i]; lds[i] = run; run += c; }
  }
  __syncthreads();
  int ex = inc - v + lds[wid];
  if (t < NBK) { bktBase[t] = ex; cursor[t] = ex; }
  if (t == NBK) bktBase[NBK] = ex;  // == N_EDGES
}

// Pass B: scatter packed (src | tgtLocal<<17) into bucket regions.
// Per-block LDS histogram -> one global-atomic range reservation per bucket ->
// contiguous ~21-entry runs per (block,bucket).
__global__ __launch_bounds__(256) void bin_scatter(const int* __restrict__ src,
                                                   const int* __restrict__ tgt,
                                                   int* __restrict__ cursor,
                                                   unsigned int* __restrict__ binned) {
  __shared__ int hist[NBK];
  __shared__ int lbase[NBK];
  int t = threadIdx.x;
  for (int i = t; i < NBK; i += 256) hist[i] = 0;
  __syncthreads();
  int e0 = blockIdx.x * EPB;
  int e1 = min(e0 + EPB, N_EDGES);
  for (int e = e0 + t; e < e1; e += 256) atomicAdd(&hist[tgt[e] >> 8], 1);
  __syncthreads();
  for (int i = t; i < NBK; i += 256) {
    int c = hist[i];
    lbase[i] = c ? atomicAdd(&cursor[i], c) : 0;
    hist[i] = 0;  // reuse as local cursor
  }
  __syncthreads();
  for (int e = e0 + t; e < e1; e += 256) {
    int tg = tgt[e];
    int bkt = tg >> 8;
    int lo = atomicAdd(&hist[bkt], 1);
    binned[lbase[bkt] + lo] = (unsigned int)src[e] | ((unsigned int)(tg & 255) << 17);
  }
}

// Pass C: one block per bucket. Local degree count + scan -> offs, then place
// src ids into csr (writes confined to the bucket's ~32KB L2-resident window).
__global__ __launch_bounds__(256) void bucket_sort(const unsigned int* __restrict__ binned,
                                                   const int* __restrict__ bktBase,
                                                   int* __restrict__ csr,
                                                   int* __restrict__ offs) {
  __shared__ int deg[256];
  __shared__ int lcur[256];
  __shared__ int wsum[4];
  int b = blockIdx.x;
  int t = threadIdx.x;
  int base = bktBase[b];
  int cnt = bktBase[b + 1] - base;
  deg[t] = 0;
  __syncthreads();
  for (int i = t; i < cnt; i += 256) atomicAdd(&deg[binned[base + i] >> 17], 1);
  __syncthreads();
  int v = deg[t];
  int inc = wave_incl_scan_i(v);
  int lane = t & 63, wid = t >> 6;
  if (lane == 63) wsum[wid] = inc;
  __syncthreads();
  if (t == 0) {
    int run = 0;
#pragma unroll
    for (int i = 0; i < 4; i++) { int c = wsum[i]; wsum[i] = run; run += c; }
  }
  __syncthreads();
  int incl = inc + wsum[wid];
  lcur[t] = base + incl - v;  // exclusive start
  int node = b * 256 + t;
  if (node < N_NODES) offs[node] = base + incl;  // end position
  __syncthreads();
  for (int i = t; i < cnt; i += 256) {
    unsigned int pv = binned[base + i];
    int pos = atomicAdd(&lcur[pv >> 17], 1);
    csr[pos] = (int)(pv & 0x1FFFFu);
  }
}

// ==================== fused layers (CSR path) ====================

// Layer 1: wave per node. Gather-mean x (32ch, 2 edges/iter) -> 32x64 matmul
// (Wl on agg, Wr on self) -> LayerNorm(64) -> ReLU -> h1.
__global__ __launch_bounds__(256) void layer1_fused(
    const float* __restrict__ x, const int* __restrict__ csr,
    const int* __restrict__ offs, const float* __restrict__ Wl,
    const float* __restrict__ Wr, const float* __restrict__ b,
    const float* __restrict__ g, const float* __restrict__ be,
    float* __restrict__ h1) {
  int node = blockIdx.x * 4 + (threadIdx.x >> 6);
  if (node >= N_NODES) return;
  int lane = threadIdx.x & 63;
  int c = lane & 31, half = lane >> 5;

  int end = offs[node];
  int start = node ? offs[node - 1] : 0;
  float inv = 1.0f / fmaxf((float)(end - start), 1.0f);

  float acc = 0.0f;
  for (int slot = start + half; slot < end; slot += 2)
    acc += x[(size_t)csr[slot] * 32 + c];
  acc += __shfl_xor(acc, 32);  // lane holds agg[lane&31] (dup across halves)

  float xself = x[(size_t)node * 32 + c];
  int o = lane;
  float accO = b[o];
#pragma unroll
  for (int k = 0; k < 32; k++) {
    float ak = __shfl(acc, k);
    float xk = __shfl(xself, k);
    accO = fmaf(ak * inv, Wl[k * 64 + o], accO);
    accO = fmaf(xk, Wr[k * 64 + o], accO);
  }

  // LayerNorm over 64 lanes + ReLU
  float s = accO;
#pragma unroll
  for (int off = 32; off; off >>= 1) s += __shfl_xor(s, off);
  float mu = s * (1.0f / 64.0f);
  float d = accO - mu;
  float v2 = d * d;
#pragma unroll
  for (int off = 32; off; off >>= 1) v2 += __shfl_xor(v2, off);
  float o2 = d * rsqrtf(v2 * (1.0f / 64.0f) + 1e-5f) * g[o] + be[o];
  h1[(size_t)node * 64 + o] = fmaxf(o2, 0.0f);
}

// Layer 2: wave per node. Gather-mean h1 (64ch) -> 64x64 matmul -> LN -> ReLU -> h2.
__global__ __launch_bounds__(256) void layer2_fused(
    const float* __restrict__ h1, const int* __restrict__ csr,
    const int* __restrict__ offs, const float* __restrict__ Wl,
    const float* __restrict__ Wr, const float* __restrict__ b,
    const float* __restrict__ g, const float* __restrict__ be,
    float* __restrict__ h2) {
  int node = blockIdx.x * 4 + (threadIdx.x >> 6);
  if (node >= N_NODES) return;
  int lane = threadIdx.x & 63;

  int end = offs[node];
  int start = node ? offs[node - 1] : 0;
  float inv = 1.0f / fmaxf((float)(end - start), 1.0f);

  float a0 = 0.0f, a1 = 0.0f;
  int slot = start;
  for (; slot + 2 <= end; slot += 2) {
    int s0 = csr[slot], s1 = csr[slot + 1];
    a0 += h1[(size_t)s0 * 64 + lane];
    a1 += h1[(size_t)s1 * 64 + lane];
  }
  if (slot < end) a0 += h1[(size_t)csr[slot] * 64 + lane];
  float agg = a0 + a1;

  float hself = h1[(size_t)node * 64 + lane];
  int o = lane;
  float accO = b[o];
#pragma unroll
  for (int k = 0; k < 64; k++) {
    float ak = __shfl(agg, k);
    float hk = __shfl(hself, k);
    accO = fmaf(ak * inv, Wl[k * 64 + o], accO);
    accO = fmaf(hk, Wr[k * 64 + o], accO);
  }

  float s = accO;
#pragma unroll
  for (int off = 32; off; off >>= 1) s += __shfl_xor(s, off);
  float mu = s * (1.0f / 64.0f);
  float d = accO - mu;
  float v2 = d * d;
#pragma unroll
  for (int off = 32; off; off >>= 1) v2 += __shfl_xor(v2, off);
  float o2 = d * rsqrtf(v2 * (1.0f / 64.0f) + 1e-5f) * g[o] + be[o];
  h2[(size_t)node * 64 + o] = fmaxf(o2, 0.0f);
}

// Layer 3 node part: y = h2 @ W_l3 (staged), out = h2 @ W_r3 + b3 (self term).
__global__ __launch_bounds__(256) void node3(
    const float* __restrict__ h, const float* __restrict__ Wl,
    const float* __restrict__ Wr, const float* __restrict__ b,
    float* __restrict__ y, float* __restrict__ out) {
  int i = blockIdx.x * 256 + threadIdx.x;
  if (i >= N_NODES) return;
  const float* hr = h + (size_t)i * 64;
  float y0 = 0.f, y1 = 0.f, r0 = b[0], r1 = b[1];
#pragma unroll
  for (int k = 0; k < 64; k++) {
    float hv = hr[k];
    y0 = fmaf(hv, Wl[k * 2 + 0], y0);
    y1 = fmaf(hv, Wl[k * 2 + 1], y1);
    r0 = fmaf(hv, Wr[k * 2 + 0], r0);
    r1 = fmaf(hv, Wr[k * 2 + 1], r1);
  }
  reinterpret_cast<float2*>(y)[i] = make_float2(y0, y1);
  reinterpret_cast<float2*>(out)[i] = make_float2(r0, r1);
}

// Layer 3 gather: wave per node, edges strided across lanes, shfl reduce.
__global__ __launch_bounds__(256) void gather3(
    const float* __restrict__ y, const int* __restrict__ csr,
    const int* __restrict__ offs, float* __restrict__ out) {
  int node = blockIdx.x * 4 + (threadIdx.x >> 6);
  if (node >= N_NODES) return;
  int lane = threadIdx.x & 63;

  int end = offs[node];
  int start = node ? offs[node - 1] : 0;
  float inv = 1.0f / fmaxf((float)(end - start), 1.0f);

  float s0 = 0.f, s1 = 0.f;
  for (int slot = start + lane; slot < end; slot += 64) {
    float2 v = reinterpret_cast<const float2*>(y)[csr[slot]];
    s0 += v.x;
    s1 += v.y;
  }
#pragma unroll
  for (int off = 32; off; off >>= 1) {
    s0 += __shfl_xor(s0, off);
    s1 += __shfl_xor(s1, off);
  }
  if (lane == 0) {
    out[(size_t)node * 2 + 0] += s0 * inv;
    out[(size_t)node * 2 + 1] += s1 * inv;
  }
}

// ==================== fallback atomic path (round-1) ====================

__global__ __launch_bounds__(256) void scatter1(
    const int* __restrict__ src, const int* __restrict__ tgt,
    const float* __restrict__ x, float* __restrict__ agg, float* __restrict__ deg) {
  int tid = blockIdx.x * blockDim.x + threadIdx.x;
  if (tid >= N_EDGES * 8) return;
  int e = tid >> 3, q = tid & 7;
  int s = src[e], t = tgt[e];
  float4 v = reinterpret_cast<const float4*>(x)[s * 8 + q];
  float* a = agg + t * 32 + q * 4;
  atomicAdd(a + 0, v.x);
  atomicAdd(a + 1, v.y);
  atomicAdd(a + 2, v.z);
  atomicAdd(a + 3, v.w);
  if (q == 0) atomicAdd(deg + t, 1.0f);
}

__global__ __launch_bounds__(256) void scatter2(
    const int* __restrict__ src, const int* __restrict__ tgt,
    const float* __restrict__ h, float* __restrict__ agg) {
  int tid = blockIdx.x * blockDim.x + threadIdx.x;
  if (tid >= N_EDGES * 16) return;
  int e = tid >> 4, q = tid & 15;
  int s = src[e], t = tgt[e];
  float4 v = reinterpret_cast<const float4*>(h)[s * 16 + q];
  float* a = agg + t * 64 + q * 4;
  atomicAdd(a + 0, v.x);
  atomicAdd(a + 1, v.y);
  atomicAdd(a + 2, v.z);
  atomicAdd(a + 3, v.w);
}

__global__ __launch_bounds__(256) void scatter3(
    const int* __restrict__ src, const int* __restrict__ tgt,
    const float* __restrict__ y, const float* __restrict__ invdeg,
    float* __restrict__ out) {
  int e = blockIdx.x * blockDim.x + threadIdx.x;
  if (e >= N_EDGES) return;
  int s = src[e], t = tgt[e];
  float2 v = reinterpret_cast<const float2*>(y)[s];
  float inv = invdeg[t];
  atomicAdd(out + t * 2 + 0, v.x * inv);
  atomicAdd(out + t * 2 + 1, v.y * inv);
}

template <int CIN, int LAYER1>
__global__ __launch_bounds__(256) void node_ln(
    const float* __restrict__ xin, const float* __restrict__ agg,
    float* __restrict__ deg, const float* __restrict__ Wl,
    const float* __restrict__ Wr, const float* __restrict__ b,
    const float* __restrict__ g, const float* __restrict__ be,
    float* __restrict__ hout) {
  int gid = blockIdx.x * blockDim.x + threadIdx.x;
  int node = gid >> 6;
  int c = threadIdx.x & 63;
  if (node >= N_NODES) return;

  float inv;
  if (LAYER1) {
    float dg = deg[node];
    inv = 1.0f / fmaxf(dg, 1.0f);
    if (c == 0) deg[node] = inv;
  } else {
    inv = deg[node];
  }

  const float* xr = xin + (size_t)node * CIN;
  const float* ar = agg + (size_t)node * CIN;
  float acc = b[c];
#pragma unroll
  for (int k = 0; k < CIN; k++) {
    acc = fmaf(ar[k] * inv, Wl[k * 64 + c], acc);
    acc = fmaf(xr[k], Wr[k * 64 + c], acc);
  }

  float s = acc;
#pragma unroll
  for (int off = 32; off; off >>= 1) s += __shfl_xor(s, off);
  float mu = s * (1.0f / 64.0f);
  float d = acc - mu;
  float v2 = d * d;
#pragma unroll
  for (int off = 32; off; off >>= 1) v2 += __shfl_xor(v2, off);
  float var = v2 * (1.0f / 64.0f);
  float o = d * rsqrtf(var + 1e-5f) * g[c] + be[c];
  hout[(size_t)node * 64 + c] = fmaxf(o, 0.0f);
}

// ==================== launch ====================

extern "C" void kernel_launch(void* const* d_in, const int* in_sizes, int n_in,
                              void* d_out, int out_size, void* d_ws, size_t ws_size,
                              hipStream_t stream) {
  const float* x = (const float*)d_in[0];
  const int* ei = (const int*)d_in[1];
  const int* src = ei;
  const int* tgt = ei + N_EDGES;
  const float* Wl1 = (const float*)d_in[2];
  const float* Wr1 = (const float*)d_in[3];
  const float* b1 = (const float*)d_in[4];
  const float* g1 = (const float*)d_in[5];
  const float* be1 = (const float*)d_in[6];
  const float* Wl2 = (const float*)d_in[7];
  const float* Wr2 = (const float*)d_in[8];
  const float* b2 = (const float*)d_in[9];
  const float* g2 = (const float*)d_in[10];
  const float* be2 = (const float*)d_in[11];
  const float* Wl3 = (const float*)d_in[12];
  const float* Wr3 = (const float*)d_in[13];
  const float* b3 = (const float*)d_in[14];
  float* out = (float*)d_out;
  char* ws = (char*)d_ws;

  // ---- CSR-path workspace layout ----
  size_t p = 0;
  auto carve = [&](size_t bytes) {
    size_t r = p;
    p += (bytes + 255) & ~(size_t)255;
    return r;
  };
  size_t count_off = carve((size_t)NBK * 4);
  size_t base_off = carve((size_t)(NBK + 1) * 4);
  size_t cursor_off = carve((size_t)NBK * 4);
  size_t offs_off = carve((size_t)N_NODES * 4);
  size_t csr_off = carve((size_t)N_EDGES * 4);
  size_t B_off = carve((size_t)N_NODES * 64 * 4);  // h1 / y3; binned aliases front half
  size_t A_off = carve((size_t)N_NODES * 64 * 4);  // h2
  size_t need_csr = p;

  const int NB = (N_NODES + 255) / 256;  // 391

  if (ws_size >= need_csr) {
    int* count = (int*)(ws + count_off);
    int* bktBase = (int*)(ws + base_off);
    int* cursor = (int*)(ws + cursor_off);
    int* offs = (int*)(ws + offs_off);
    int* csr = (int*)(ws + csr_off);
    float* B = (float*)(ws + B_off);
    float* A = (float*)(ws + A_off);
    unsigned int* binned = (unsigned int*)B;  // 12.8MB, dead before h1 is written

    hipMemsetAsync(count, 0, (size_t)NBK * 4, stream);
    bin_hist<<<NBLK_BIN, 256, 0, stream>>>(tgt, count);
    bin_scan<<<1, 512, 0, stream>>>(count, bktBase, cursor);
    bin_scatter<<<NBLK_BIN, 256, 0, stream>>>(src, tgt, cursor, binned);
    bucket_sort<<<NBK, 256, 0, stream>>>(binned, bktBase, csr, offs);

    layer1_fused<<<(N_NODES + 3) / 4, 256, 0, stream>>>(
        x, csr, offs, Wl1, Wr1, b1, g1, be1, B);
    layer2_fused<<<(N_NODES + 3) / 4, 256, 0, stream>>>(
        B, csr, offs, Wl2, Wr2, b2, g2, be2, A);
    float* y3 = B;  // h1 dead; reuse
    node3<<<NB, 256, 0, stream>>>(A, Wl3, Wr3, b3, y3, out);
    gather3<<<(N_NODES + 3) / 4, 256, 0, stream>>>(y3, csr, offs, out);
  } else {
    // fallback: round-1 atomic path (needs ~51.7MB)
    float* deg = (float*)ws;
    float* A = (float*)(ws + (size_t)N_NODES * 4);
    float* B = A + (size_t)N_NODES * 64;

    hipMemsetAsync(deg, 0, (size_t)N_NODES * 4, stream);
    hipMemsetAsync(A, 0, (size_t)N_NODES * 32 * 4, stream);
    scatter1<<<(N_EDGES * 8 + 255) / 256, 256, 0, stream>>>(src, tgt, x, A, deg);
    node_ln<32, 1><<<(N_NODES * 64 + 255) / 256, 256, 0, stream>>>(
        x, A, deg, Wl1, Wr1, b1, g1, be1, B);
    hipMemsetAsync(A, 0, (size_t)N_NODES * 64 * 4, stream);
    scatter2<<<(N_EDGES * 16 + 255) / 256, 256, 0, stream>>>(src, tgt, B, A);
    node_ln<64, 0><<<(N_NODES * 64 + 255) / 256, 256, 0, stream>>>(
        B, A, deg, Wl2, Wr2, b2, g2, be2, B);
    float* y3 = A;
    node3<<<NB, 256, 0, stream>>>(B, Wl3, Wr3, b3, y3, out);
    scatter3<<<(N_EDGES + 255) / 256, 256, 0, stream>>>(src, tgt, y3, deg, out);
  }
}

// Round 4
// 439.107 us; speedup vs baseline: 10.5494x; 1.1521x over previous
//
#include <hip/hip_runtime.h>
#include <hip/hip_fp16.h>

#define N_NODES 100000
#define N_EDGES 3200000
#define NBK 391          // ceil(N_NODES / 256) buckets, 256 nodes each
#define EPB 8192         // edges per block in binning passes
#define NBLK_BIN 391     // ceil(N_EDGES / EPB)

// ==================== common helpers ====================

__device__ __forceinline__ int wave_incl_scan_i(int v) {
  int lane = threadIdx.x & 63;
#pragma unroll
  for (int off = 1; off < 64; off <<= 1) {
    int n = __shfl_up(v, off);
    if (lane >= off) v += n;
  }
  return v;
}

// ==================== CSR build: bucketed counting sort ====================

__global__ __launch_bounds__(256) void bin_hist(const int* __restrict__ tgt,
                                                int* __restrict__ count) {
  __shared__ int hist[NBK];
  int t = threadIdx.x;
  for (int i = t; i < NBK; i += 256) hist[i] = 0;
  __syncthreads();
  int e0 = blockIdx.x * EPB;
  int e1 = min(e0 + EPB, N_EDGES);
  for (int e = e0 + t; e < e1; e += 256) atomicAdd(&hist[tgt[e] >> 8], 1);
  __syncthreads();
  for (int i = t; i < NBK; i += 256) {
    int c = hist[i];
    if (c) atomicAdd(&count[i], c);
  }
}

__global__ __launch_bounds__(512) void bin_scan(const int* __restrict__ count,
                                                int* __restrict__ bktBase,
                                                int* __restrict__ cursor) {
  __shared__ int lds[8];
  int t = threadIdx.x;
  int v = (t < NBK) ? count[t] : 0;
  int inc = wave_incl_scan_i(v);
  int lane = t & 63, wid = t >> 6;
  if (lane == 63) lds[wid] = inc;
  __syncthreads();
  if (t == 0) {
    int run = 0;
#pragma unroll
    for (int i = 0; i < 8; i++) { int c = lds[i]; lds[i] = run; run += c; }
  }
  __syncthreads();
  int ex = inc - v + lds[wid];
  if (t < NBK) { bktBase[t] = ex; cursor[t] = ex; }
  if (t == NBK) bktBase[NBK] = ex;  // == N_EDGES
}

__global__ __launch_bounds__(256) void bin_scatter(const int* __restrict__ src,
                                                   const int* __restrict__ tgt,
                                                   int* __restrict__ cursor,
                                                   unsigned int* __restrict__ binned) {
  __shared__ int hist[NBK];
  __shared__ int lbase[NBK];
  int t = threadIdx.x;
  for (int i = t; i < NBK; i += 256) hist[i] = 0;
  __syncthreads();
  int e0 = blockIdx.x * EPB;
  int e1 = min(e0 + EPB, N_EDGES);
  for (int e = e0 + t; e < e1; e += 256) atomicAdd(&hist[tgt[e] >> 8], 1);
  __syncthreads();
  for (int i = t; i < NBK; i += 256) {
    int c = hist[i];
    lbase[i] = c ? atomicAdd(&cursor[i], c) : 0;
    hist[i] = 0;  // reuse as local cursor
  }
  __syncthreads();
  for (int e = e0 + t; e < e1; e += 256) {
    int tg = tgt[e];
    int bkt = tg >> 8;
    int lo = atomicAdd(&hist[bkt], 1);
    binned[lbase[bkt] + lo] = (unsigned int)src[e] | ((unsigned int)(tg & 255) << 17);
  }
}

__global__ __launch_bounds__(256) void bucket_sort(const unsigned int* __restrict__ binned,
                                                   const int* __restrict__ bktBase,
                                                   int* __restrict__ csr,
                                                   int* __restrict__ offs) {
  __shared__ int deg[256];
  __shared__ int lcur[256];
  __shared__ int wsum[4];
  int b = blockIdx.x;
  int t = threadIdx.x;
  int base = bktBase[b];
  int cnt = bktBase[b + 1] - base;
  deg[t] = 0;
  __syncthreads();
  for (int i = t; i < cnt; i += 256) atomicAdd(&deg[binned[base + i] >> 17], 1);
  __syncthreads();
  int v = deg[t];
  int inc = wave_incl_scan_i(v);
  int lane = t & 63, wid = t >> 6;
  if (lane == 63) wsum[wid] = inc;
  __syncthreads();
  if (t == 0) {
    int run = 0;
#pragma unroll
    for (int i = 0; i < 4; i++) { int c = wsum[i]; wsum[i] = run; run += c; }
  }
  __syncthreads();
  int incl = inc + wsum[wid];
  lcur[t] = base + incl - v;  // exclusive start
  int node = b * 256 + t;
  if (node < N_NODES) offs[node] = base + incl;  // end position
  __syncthreads();
  for (int i = t; i < cnt; i += 256) {
    unsigned int pv = binned[base + i];
    int pos = atomicAdd(&lcur[pv >> 17], 1);
    csr[pos] = (int)(pv & 0x1FFFFu);
  }
}

// ==================== fp16 conversion ====================

__global__ __launch_bounds__(256) void to_half2(const float* __restrict__ in,
                                                __half2* __restrict__ out, int n2) {
  int i = blockIdx.x * 256 + threadIdx.x;
  if (i >= n2) return;
  float2 v = reinterpret_cast<const float2*>(in)[i];
  out[i] = __floats2half2_rn(v.x, v.y);
}

// ==================== fused layers (CSR path, fp16 gather) ====================

// Layer 1: wave per node. x stored fp16 (16 half2/row). lane = slot4*16 + c:
// 4 edges per iteration, lane holds channel pair (2c, 2c+1).
__global__ __launch_bounds__(256) void layer1_fused(
    const __half2* __restrict__ xh, const int* __restrict__ csr,
    const int* __restrict__ offs, const float* __restrict__ Wl,
    const float* __restrict__ Wr, const float* __restrict__ b,
    const float* __restrict__ g, const float* __restrict__ be,
    __half* __restrict__ h1) {
  int node = blockIdx.x * 4 + (threadIdx.x >> 6);
  if (node >= N_NODES) return;
  int lane = threadIdx.x & 63;
  int c = lane & 15, slot4 = lane >> 4;

  int end = offs[node];
  int start = node ? offs[node - 1] : 0;
  float inv = 1.0f / fmaxf((float)(end - start), 1.0f);

  float ax = 0.0f, ay = 0.0f;
  for (int slot = start + slot4; slot < end; slot += 4) {
    float2 f = __half22float2(xh[(size_t)csr[slot] * 16 + c]);
    ax += f.x;
    ay += f.y;
  }
  ax += __shfl_xor(ax, 16); ay += __shfl_xor(ay, 16);
  ax += __shfl_xor(ax, 32); ay += __shfl_xor(ay, 32);

  float2 xs = __half22float2(xh[(size_t)node * 16 + c]);

  int o = lane;
  float accO = b[o];
#pragma unroll
  for (int k = 0; k < 32; k++) {
    float ak = __shfl((k & 1) ? ay : ax, k >> 1);
    float xk = __shfl((k & 1) ? xs.y : xs.x, k >> 1);
    accO = fmaf(ak * inv, Wl[k * 64 + o], accO);
    accO = fmaf(xk, Wr[k * 64 + o], accO);
  }

  // LayerNorm over 64 lanes + ReLU
  float s = accO;
#pragma unroll
  for (int off = 32; off; off >>= 1) s += __shfl_xor(s, off);
  float mu = s * (1.0f / 64.0f);
  float d = accO - mu;
  float v2 = d * d;
#pragma unroll
  for (int off = 32; off; off >>= 1) v2 += __shfl_xor(v2, off);
  float o2 = d * rsqrtf(v2 * (1.0f / 64.0f) + 1e-5f) * g[o] + be[o];
  h1[(size_t)node * 64 + o] = __float2half(fmaxf(o2, 0.0f));
}

// Layer 2: wave per node. h1 fp16 (32 half2/row). lane = half*32 + c:
// 2 edges per iteration, lane holds channel pair (2c, 2c+1).
__global__ __launch_bounds__(256) void layer2_fused(
    const __half2* __restrict__ h1, const int* __restrict__ csr,
    const int* __restrict__ offs, const float* __restrict__ Wl,
    const float* __restrict__ Wr, const float* __restrict__ b,
    const float* __restrict__ g, const float* __restrict__ be,
    float* __restrict__ h2) {
  int node = blockIdx.x * 4 + (threadIdx.x >> 6);
  if (node >= N_NODES) return;
  int lane = threadIdx.x & 63;
  int c = lane & 31, half = lane >> 5;

  int end = offs[node];
  int start = node ? offs[node - 1] : 0;
  float inv = 1.0f / fmaxf((float)(end - start), 1.0f);

  float ax = 0.0f, ay = 0.0f;
  for (int slot = start + half; slot < end; slot += 2) {
    float2 f = __half22float2(h1[(size_t)csr[slot] * 32 + c]);
    ax += f.x;
    ay += f.y;
  }
  ax += __shfl_xor(ax, 32);
  ay += __shfl_xor(ay, 32);

  float2 hs = __half22float2(h1[(size_t)node * 32 + c]);

  int o = lane;
  float accO = b[o];
#pragma unroll
  for (int k = 0; k < 64; k++) {
    float ak = __shfl((k & 1) ? ay : ax, k >> 1);
    float hk = __shfl((k & 1) ? hs.y : hs.x, k >> 1);
    accO = fmaf(ak * inv, Wl[k * 64 + o], accO);
    accO = fmaf(hk, Wr[k * 64 + o], accO);
  }

  float s = accO;
#pragma unroll
  for (int off = 32; off; off >>= 1) s += __shfl_xor(s, off);
  float mu = s * (1.0f / 64.0f);
  float d = accO - mu;
  float v2 = d * d;
#pragma unroll
  for (int off = 32; off; off >>= 1) v2 += __shfl_xor(v2, off);
  float o2 = d * rsqrtf(v2 * (1.0f / 64.0f) + 1e-5f) * g[o] + be[o];
  h2[(size_t)node * 64 + o] = fmaxf(o2, 0.0f);
}

// Layer 3 node part: y = h2 @ W_l3 (staged), out = h2 @ W_r3 + b3 (self term).
__global__ __launch_bounds__(256) void node3(
    const float* __restrict__ h, const float* __restrict__ Wl,
    const float* __restrict__ Wr, const float* __restrict__ b,
    float* __restrict__ y, float* __restrict__ out) {
  int i = blockIdx.x * 256 + threadIdx.x;
  if (i >= N_NODES) return;
  const float* hr = h + (size_t)i * 64;
  float y0 = 0.f, y1 = 0.f, r0 = b[0], r1 = b[1];
#pragma unroll
  for (int k = 0; k < 64; k++) {
    float hv = hr[k];
    y0 = fmaf(hv, Wl[k * 2 + 0], y0);
    y1 = fmaf(hv, Wl[k * 2 + 1], y1);
    r0 = fmaf(hv, Wr[k * 2 + 0], r0);
    r1 = fmaf(hv, Wr[k * 2 + 1], r1);
  }
  reinterpret_cast<float2*>(y)[i] = make_float2(y0, y1);
  reinterpret_cast<float2*>(out)[i] = make_float2(r0, r1);
}

// Layer 3 gather: wave per node, edges strided across lanes, shfl reduce.
__global__ __launch_bounds__(256) void gather3(
    const float* __restrict__ y, const int* __restrict__ csr,
    const int* __restrict__ offs, float* __restrict__ out) {
  int node = blockIdx.x * 4 + (threadIdx.x >> 6);
  if (node >= N_NODES) return;
  int lane = threadIdx.x & 63;

  int end = offs[node];
  int start = node ? offs[node - 1] : 0;
  float inv = 1.0f / fmaxf((float)(end - start), 1.0f);

  float s0 = 0.f, s1 = 0.f;
  for (int slot = start + lane; slot < end; slot += 64) {
    float2 v = reinterpret_cast<const float2*>(y)[csr[slot]];
    s0 += v.x;
    s1 += v.y;
  }
#pragma unroll
  for (int off = 32; off; off >>= 1) {
    s0 += __shfl_xor(s0, off);
    s1 += __shfl_xor(s1, off);
  }
  if (lane == 0) {
    out[(size_t)node * 2 + 0] += s0 * inv;
    out[(size_t)node * 2 + 1] += s1 * inv;
  }
}

// ==================== fallback atomic path (round-1) ====================

__global__ __launch_bounds__(256) void scatter1(
    const int* __restrict__ src, const int* __restrict__ tgt,
    const float* __restrict__ x, float* __restrict__ agg, float* __restrict__ deg) {
  int tid = blockIdx.x * blockDim.x + threadIdx.x;
  if (tid >= N_EDGES * 8) return;
  int e = tid >> 3, q = tid & 7;
  int s = src[e], t = tgt[e];
  float4 v = reinterpret_cast<const float4*>(x)[s * 8 + q];
  float* a = agg + t * 32 + q * 4;
  atomicAdd(a + 0, v.x);
  atomicAdd(a + 1, v.y);
  atomicAdd(a + 2, v.z);
  atomicAdd(a + 3, v.w);
  if (q == 0) atomicAdd(deg + t, 1.0f);
}

__global__ __launch_bounds__(256) void scatter2(
    const int* __restrict__ src, const int* __restrict__ tgt,
    const float* __restrict__ h, float* __restrict__ agg) {
  int tid = blockIdx.x * blockDim.x + threadIdx.x;
  if (tid >= N_EDGES * 16) return;
  int e = tid >> 4, q = tid & 15;
  int s = src[e], t = tgt[e];
  float4 v = reinterpret_cast<const float4*>(h)[s * 16 + q];
  float* a = agg + t * 64 + q * 4;
  atomicAdd(a + 0, v.x);
  atomicAdd(a + 1, v.y);
  atomicAdd(a + 2, v.z);
  atomicAdd(a + 3, v.w);
}

__global__ __launch_bounds__(256) void scatter3(
    const int* __restrict__ src, const int* __restrict__ tgt,
    const float* __restrict__ y, const float* __restrict__ invdeg,
    float* __restrict__ out) {
  int e = blockIdx.x * blockDim.x + threadIdx.x;
  if (e >= N_EDGES) return;
  int s = src[e], t = tgt[e];
  float2 v = reinterpret_cast<const float2*>(y)[s];
  float inv = invdeg[t];
  atomicAdd(out + t * 2 + 0, v.x * inv);
  atomicAdd(out + t * 2 + 1, v.y * inv);
}

template <int CIN, int LAYER1>
__global__ __launch_bounds__(256) void node_ln(
    const float* __restrict__ xin, const float* __restrict__ agg,
    float* __restrict__ deg, const float* __restrict__ Wl,
    const float* __restrict__ Wr, const float* __restrict__ b,
    const float* __restrict__ g, const float* __restrict__ be,
    float* __restrict__ hout) {
  int gid = blockIdx.x * blockDim.x + threadIdx.x;
  int node = gid >> 6;
  int c = threadIdx.x & 63;
  if (node >= N_NODES) return;

  float inv;
  if (LAYER1) {
    float dg = deg[node];
    inv = 1.0f / fmaxf(dg, 1.0f);
    if (c == 0) deg[node] = inv;
  } else {
    inv = deg[node];
  }

  const float* xr = xin + (size_t)node * CIN;
  const float* ar = agg + (size_t)node * CIN;
  float acc = b[c];
#pragma unroll
  for (int k = 0; k < CIN; k++) {
    acc = fmaf(ar[k] * inv, Wl[k * 64 + c], acc);
    acc = fmaf(xr[k], Wr[k * 64 + c], acc);
  }

  float s = acc;
#pragma unroll
  for (int off = 32; off; off >>= 1) s += __shfl_xor(s, off);
  float mu = s * (1.0f / 64.0f);
  float d = acc - mu;
  float v2 = d * d;
#pragma unroll
  for (int off = 32; off; off >>= 1) v2 += __shfl_xor(v2, off);
  float var = v2 * (1.0f / 64.0f);
  float o = d * rsqrtf(var + 1e-5f) * g[c] + be[c];
  hout[(size_t)node * 64 + c] = fmaxf(o, 0.0f);
}

// ==================== launch ====================

extern "C" void kernel_launch(void* const* d_in, const int* in_sizes, int n_in,
                              void* d_out, int out_size, void* d_ws, size_t ws_size,
                              hipStream_t stream) {
  const float* x = (const float*)d_in[0];
  const int* ei = (const int*)d_in[1];
  const int* src = ei;
  const int* tgt = ei + N_EDGES;
  const float* Wl1 = (const float*)d_in[2];
  const float* Wr1 = (const float*)d_in[3];
  const float* b1 = (const float*)d_in[4];
  const float* g1 = (const float*)d_in[5];
  const float* be1 = (const float*)d_in[6];
  const float* Wl2 = (const float*)d_in[7];
  const float* Wr2 = (const float*)d_in[8];
  const float* b2 = (const float*)d_in[9];
  const float* g2 = (const float*)d_in[10];
  const float* be2 = (const float*)d_in[11];
  const float* Wl3 = (const float*)d_in[12];
  const float* Wr3 = (const float*)d_in[13];
  const float* b3 = (const float*)d_in[14];
  float* out = (float*)d_out;
  char* ws = (char*)d_ws;

  // ---- CSR-path workspace layout ----
  size_t p = 0;
  auto carve = [&](size_t bytes) {
    size_t r = p;
    p += (bytes + 255) & ~(size_t)255;
    return r;
  };
  size_t count_off = carve((size_t)NBK * 4);
  size_t base_off = carve((size_t)(NBK + 1) * 4);
  size_t cursor_off = carve((size_t)NBK * 4);
  size_t offs_off = carve((size_t)N_NODES * 4);
  size_t csr_off = carve((size_t)N_EDGES * 4);
  size_t xh_off = carve((size_t)N_NODES * 32 * 2);   // x fp16; later y3 (800KB)
  size_t h1_off = carve((size_t)N_NODES * 64 * 2);   // h1 fp16
  size_t h2_off = carve((size_t)N_NODES * 64 * 4);   // h2 f32; binned aliases front
  size_t need_csr = p;

  const int NB = (N_NODES + 255) / 256;  // 391

  if (ws_size >= need_csr) {
    int* count = (int*)(ws + count_off);
    int* bktBase = (int*)(ws + base_off);
    int* cursor = (int*)(ws + cursor_off);
    int* offs = (int*)(ws + offs_off);
    int* csr = (int*)(ws + csr_off);
    __half2* xh = (__half2*)(ws + xh_off);
    __half* h1 = (__half*)(ws + h1_off);
    float* h2 = (float*)(ws + h2_off);
    unsigned int* binned = (unsigned int*)h2;  // 12.8MB, dead before h2 is written

    hipMemsetAsync(count, 0, (size_t)NBK * 4, stream);
    bin_hist<<<NBLK_BIN, 256, 0, stream>>>(tgt, count);
    bin_scan<<<1, 512, 0, stream>>>(count, bktBase, cursor);
    bin_scatter<<<NBLK_BIN, 256, 0, stream>>>(src, tgt, cursor, binned);
    bucket_sort<<<NBK, 256, 0, stream>>>(binned, bktBase, csr, offs);

    to_half2<<<(N_NODES * 16 + 255) / 256, 256, 0, stream>>>(x, xh, N_NODES * 16);

    layer1_fused<<<(N_NODES + 3) / 4, 256, 0, stream>>>(
        xh, csr, offs, Wl1, Wr1, b1, g1, be1, h1);
    layer2_fused<<<(N_NODES + 3) / 4, 256, 0, stream>>>(
        (const __half2*)h1, csr, offs, Wl2, Wr2, b2, g2, be2, h2);
    float* y3 = (float*)xh;  // xh dead; reuse (800KB)
    node3<<<NB, 256, 0, stream>>>(h2, Wl3, Wr3, b3, y3, out);
    gather3<<<(N_NODES + 3) / 4, 256, 0, stream>>>(y3, csr, offs, out);
  } else {
    // fallback: round-1 atomic path (needs ~51.7MB)
    float* deg = (float*)ws;
    float* A = (float*)(ws + (size_t)N_NODES * 4);
    float* B = A + (size_t)N_NODES * 64;

    hipMemsetAsync(deg, 0, (size_t)N_NODES * 4, stream);
    hipMemsetAsync(A, 0, (size_t)N_NODES * 32 * 4, stream);
    scatter1<<<(N_EDGES * 8 + 255) / 256, 256, 0, stream>>>(src, tgt, x, A, deg);
    node_ln<32, 1><<<(N_NODES * 64 + 255) / 256, 256, 0, stream>>>(
        x, A, deg, Wl1, Wr1, b1, g1, be1, B);
    hipMemsetAsync(A, 0, (size_t)N_NODES * 64 * 4, stream);
    scatter2<<<(N_EDGES * 16 + 255) / 256, 256, 0, stream>>>(src, tgt, B, A);
    node_ln<64, 0><<<(N_NODES * 64 + 255) / 256, 256, 0, stream>>>(
        B, A, deg, Wl2, Wr2, b2, g2, be2, B);
    float* y3 = A;
    node3<<<NB, 256, 0, stream>>>(B, Wl3, Wr3, b3, y3, out);
    scatter3<<<(N_EDGES + 255) / 256, 256, 0, stream>>>(src, tgt, y3, deg, out);
  }
}

// Round 5
// 374.522 us; speedup vs baseline: 12.3686x; 1.1724x over previous
//
#include <hip/hip_runtime.h>
#include <hip/hip_fp16.h>

#define N_NODES 100000
#define N_EDGES 3200000
#define NBK 391          // ceil(N_NODES / 256) buckets, 256 nodes each
#define EPB 8192         // edges per block in binning passes
#define NBLK_BIN 391     // ceil(N_EDGES / EPB)

// ==================== common helpers ====================

__device__ __forceinline__ int wave_incl_scan_i(int v) {
  int lane = threadIdx.x & 63;
#pragma unroll
  for (int off = 1; off < 64; off <<= 1) {
    int n = __shfl_up(v, off);
    if (lane >= off) v += n;
  }
  return v;
}

// ==================== CSR build: bucketed counting sort ====================

__global__ __launch_bounds__(256) void bin_hist(const int* __restrict__ tgt,
                                                int* __restrict__ count) {
  __shared__ int hist[NBK];
  int t = threadIdx.x;
  for (int i = t; i < NBK; i += 256) hist[i] = 0;
  __syncthreads();
  int e0 = blockIdx.x * EPB;
  int e1 = min(e0 + EPB, N_EDGES);
  for (int e = e0 + t; e < e1; e += 256) atomicAdd(&hist[tgt[e] >> 8], 1);
  __syncthreads();
  for (int i = t; i < NBK; i += 256) {
    int c = hist[i];
    if (c) atomicAdd(&count[i], c);
  }
}

__global__ __launch_bounds__(512) void bin_scan(const int* __restrict__ count,
                                                int* __restrict__ bktBase,
                                                int* __restrict__ cursor) {
  __shared__ int lds[8];
  int t = threadIdx.x;
  int v = (t < NBK) ? count[t] : 0;
  int inc = wave_incl_scan_i(v);
  int lane = t & 63, wid = t >> 6;
  if (lane == 63) lds[wid] = inc;
  __syncthreads();
  if (t == 0) {
    int run = 0;
#pragma unroll
    for (int i = 0; i < 8; i++) { int c = lds[i]; lds[i] = run; run += c; }
  }
  __syncthreads();
  int ex = inc - v + lds[wid];
  if (t < NBK) { bktBase[t] = ex; cursor[t] = ex; }
  if (t == NBK) bktBase[NBK] = ex;  // == N_EDGES
}

__global__ __launch_bounds__(256) void bin_scatter(const int* __restrict__ src,
                                                   const int* __restrict__ tgt,
                                                   int* __restrict__ cursor,
                                                   unsigned int* __restrict__ binned) {
  __shared__ int hist[NBK];
  __shared__ int lbase[NBK];
  int t = threadIdx.x;
  for (int i = t; i < NBK; i += 256) hist[i] = 0;
  __syncthreads();
  int e0 = blockIdx.x * EPB;
  int e1 = min(e0 + EPB, N_EDGES);
  for (int e = e0 + t; e < e1; e += 256) atomicAdd(&hist[tgt[e] >> 8], 1);
  __syncthreads();
  for (int i = t; i < NBK; i += 256) {
    int c = hist[i];
    lbase[i] = c ? atomicAdd(&cursor[i], c) : 0;
    hist[i] = 0;  // reuse as local cursor
  }
  __syncthreads();
  for (int e = e0 + t; e < e1; e += 256) {
    int tg = tgt[e];
    int bkt = tg >> 8;
    int lo = atomicAdd(&hist[bkt], 1);
    binned[lbase[bkt] + lo] = (unsigned int)src[e] | ((unsigned int)(tg & 255) << 17);
  }
}

__global__ __launch_bounds__(256) void bucket_sort(const unsigned int* __restrict__ binned,
                                                   const int* __restrict__ bktBase,
                                                   int* __restrict__ csr,
                                                   int* __restrict__ offs) {
  __shared__ int deg[256];
  __shared__ int lcur[256];
  __shared__ int wsum[4];
  int b = blockIdx.x;
  int t = threadIdx.x;
  int base = bktBase[b];
  int cnt = bktBase[b + 1] - base;
  deg[t] = 0;
  __syncthreads();
  for (int i = t; i < cnt; i += 256) atomicAdd(&deg[binned[base + i] >> 17], 1);
  __syncthreads();
  int v = deg[t];
  int inc = wave_incl_scan_i(v);
  int lane = t & 63, wid = t >> 6;
  if (lane == 63) wsum[wid] = inc;
  __syncthreads();
  if (t == 0) {
    int run = 0;
#pragma unroll
    for (int i = 0; i < 4; i++) { int c = wsum[i]; wsum[i] = run; run += c; }
  }
  __syncthreads();
  int incl = inc + wsum[wid];
  lcur[t] = base + incl - v;  // exclusive start
  int node = b * 256 + t;
  if (node < N_NODES) offs[node] = base + incl;  // end position
  __syncthreads();
  for (int i = t; i < cnt; i += 256) {
    unsigned int pv = binned[base + i];
    int pos = atomicAdd(&lcur[pv >> 17], 1);
    csr[pos] = (int)(pv & 0x1FFFFu);
  }
}

// ==================== fp16 conversion ====================

__global__ __launch_bounds__(256) void to_half2(const float* __restrict__ in,
                                                __half2* __restrict__ out, int n2) {
  int i = blockIdx.x * 256 + threadIdx.x;
  if (i >= n2) return;
  float2 v = reinterpret_cast<const float2*>(in)[i];
  out[i] = __floats2half2_rn(v.x, v.y);
}

// ==================== fused layers (CSR path, fp16 gather, MLP-unrolled) ====================

// Layer 1: wave per node. x fp16 (16 half2/row). Quarter-wave (16 lanes) per row,
// 4 edges per stride; unroll 4 -> 16 rows in flight per wave iteration.
__global__ __launch_bounds__(256) void layer1_fused(
    const __half2* __restrict__ xh, const int* __restrict__ csr,
    const int* __restrict__ offs, const float* __restrict__ Wl,
    const float* __restrict__ Wr, const float* __restrict__ b,
    const float* __restrict__ g, const float* __restrict__ be,
    __half* __restrict__ h1) {
  int node = blockIdx.x * 4 + (threadIdx.x >> 6);
  if (node >= N_NODES) return;
  int lane = threadIdx.x & 63;
  int c = lane & 15, slot4 = lane >> 4;

  int end = offs[node];
  int start = node ? offs[node - 1] : 0;
  float inv = 1.0f / fmaxf((float)(end - start), 1.0f);

  float ax = 0.0f, ay = 0.0f;
  int slot = start + slot4;
  for (; slot + 12 < end; slot += 16) {
    int s0 = csr[slot], s1 = csr[slot + 4], s2 = csr[slot + 8], s3 = csr[slot + 12];
    float2 f0 = __half22float2(xh[(size_t)s0 * 16 + c]);
    float2 f1 = __half22float2(xh[(size_t)s1 * 16 + c]);
    float2 f2 = __half22float2(xh[(size_t)s2 * 16 + c]);
    float2 f3 = __half22float2(xh[(size_t)s3 * 16 + c]);
    ax += (f0.x + f1.x) + (f2.x + f3.x);
    ay += (f0.y + f1.y) + (f2.y + f3.y);
  }
  for (; slot < end; slot += 4) {
    float2 f = __half22float2(xh[(size_t)csr[slot] * 16 + c]);
    ax += f.x;
    ay += f.y;
  }
  ax += __shfl_xor(ax, 16); ay += __shfl_xor(ay, 16);
  ax += __shfl_xor(ax, 32); ay += __shfl_xor(ay, 32);

  float2 xs = __half22float2(xh[(size_t)node * 16 + c]);

  int o = lane;
  float accO = b[o];
#pragma unroll
  for (int k = 0; k < 32; k++) {
    float ak = __shfl((k & 1) ? ay : ax, k >> 1);
    float xk = __shfl((k & 1) ? xs.y : xs.x, k >> 1);
    accO = fmaf(ak * inv, Wl[k * 64 + o], accO);
    accO = fmaf(xk, Wr[k * 64 + o], accO);
  }

  // LayerNorm over 64 lanes + ReLU
  float s = accO;
#pragma unroll
  for (int off = 32; off; off >>= 1) s += __shfl_xor(s, off);
  float mu = s * (1.0f / 64.0f);
  float d = accO - mu;
  float v2 = d * d;
#pragma unroll
  for (int off = 32; off; off >>= 1) v2 += __shfl_xor(v2, off);
  float o2 = d * rsqrtf(v2 * (1.0f / 64.0f) + 1e-5f) * g[o] + be[o];
  h1[(size_t)node * 64 + o] = __float2half(fmaxf(o2, 0.0f));
}

// Layer 2: wave per node. h1 fp16 (32 half2/row). Half-wave (32 lanes) per row,
// 2 edges per stride; unroll 4 -> 8 rows in flight per wave iteration.
__global__ __launch_bounds__(256) void layer2_fused(
    const __half2* __restrict__ h1, const int* __restrict__ csr,
    const int* __restrict__ offs, const float* __restrict__ Wl,
    const float* __restrict__ Wr, const float* __restrict__ b,
    const float* __restrict__ g, const float* __restrict__ be,
    float* __restrict__ h2) {
  int node = blockIdx.x * 4 + (threadIdx.x >> 6);
  if (node >= N_NODES) return;
  int lane = threadIdx.x & 63;
  int c = lane & 31, half = lane >> 5;

  int end = offs[node];
  int start = node ? offs[node - 1] : 0;
  float inv = 1.0f / fmaxf((float)(end - start), 1.0f);

  float ax = 0.0f, ay = 0.0f;
  int slot = start + half;
  for (; slot + 6 < end; slot += 8) {
    int s0 = csr[slot], s1 = csr[slot + 2], s2 = csr[slot + 4], s3 = csr[slot + 6];
    float2 f0 = __half22float2(h1[(size_t)s0 * 32 + c]);
    float2 f1 = __half22float2(h1[(size_t)s1 * 32 + c]);
    float2 f2 = __half22float2(h1[(size_t)s2 * 32 + c]);
    float2 f3 = __half22float2(h1[(size_t)s3 * 32 + c]);
    ax += (f0.x + f1.x) + (f2.x + f3.x);
    ay += (f0.y + f1.y) + (f2.y + f3.y);
  }
  for (; slot < end; slot += 2) {
    float2 f = __half22float2(h1[(size_t)csr[slot] * 32 + c]);
    ax += f.x;
    ay += f.y;
  }
  ax += __shfl_xor(ax, 32);
  ay += __shfl_xor(ay, 32);

  float2 hs = __half22float2(h1[(size_t)node * 32 + c]);

  int o = lane;
  float accO = b[o];
#pragma unroll
  for (int k = 0; k < 64; k++) {
    float ak = __shfl((k & 1) ? ay : ax, k >> 1);
    float hk = __shfl((k & 1) ? hs.y : hs.x, k >> 1);
    accO = fmaf(ak * inv, Wl[k * 64 + o], accO);
    accO = fmaf(hk, Wr[k * 64 + o], accO);
  }

  float s = accO;
#pragma unroll
  for (int off = 32; off; off >>= 1) s += __shfl_xor(s, off);
  float mu = s * (1.0f / 64.0f);
  float d = accO - mu;
  float v2 = d * d;
#pragma unroll
  for (int off = 32; off; off >>= 1) v2 += __shfl_xor(v2, off);
  float o2 = d * rsqrtf(v2 * (1.0f / 64.0f) + 1e-5f) * g[o] + be[o];
  h2[(size_t)node * 64 + o] = fmaxf(o2, 0.0f);
}

// Layer 3 node part: y = h2 @ W_l3 (staged), out = h2 @ W_r3 + b3 (self term).
__global__ __launch_bounds__(256) void node3(
    const float* __restrict__ h, const float* __restrict__ Wl,
    const float* __restrict__ Wr, const float* __restrict__ b,
    float* __restrict__ y, float* __restrict__ out) {
  int i = blockIdx.x * 256 + threadIdx.x;
  if (i >= N_NODES) return;
  const float* hr = h + (size_t)i * 64;
  float y0 = 0.f, y1 = 0.f, r0 = b[0], r1 = b[1];
#pragma unroll
  for (int k = 0; k < 64; k++) {
    float hv = hr[k];
    y0 = fmaf(hv, Wl[k * 2 + 0], y0);
    y1 = fmaf(hv, Wl[k * 2 + 1], y1);
    r0 = fmaf(hv, Wr[k * 2 + 0], r0);
    r1 = fmaf(hv, Wr[k * 2 + 1], r1);
  }
  reinterpret_cast<float2*>(y)[i] = make_float2(y0, y1);
  reinterpret_cast<float2*>(out)[i] = make_float2(r0, r1);
}

// Layer 3 gather: wave per node, edges strided across lanes, shfl reduce.
__global__ __launch_bounds__(256) void gather3(
    const float* __restrict__ y, const int* __restrict__ csr,
    const int* __restrict__ offs, float* __restrict__ out) {
  int node = blockIdx.x * 4 + (threadIdx.x >> 6);
  if (node >= N_NODES) return;
  int lane = threadIdx.x & 63;

  int end = offs[node];
  int start = node ? offs[node - 1] : 0;
  float inv = 1.0f / fmaxf((float)(end - start), 1.0f);

  float s0 = 0.f, s1 = 0.f;
  for (int slot = start + lane; slot < end; slot += 64) {
    float2 v = reinterpret_cast<const float2*>(y)[csr[slot]];
    s0 += v.x;
    s1 += v.y;
  }
#pragma unroll
  for (int off = 32; off; off >>= 1) {
    s0 += __shfl_xor(s0, off);
    s1 += __shfl_xor(s1, off);
  }
  if (lane == 0) {
    out[(size_t)node * 2 + 0] += s0 * inv;
    out[(size_t)node * 2 + 1] += s1 * inv;
  }
}

// ==================== fallback atomic path (round-1) ====================

__global__ __launch_bounds__(256) void scatter1(
    const int* __restrict__ src, const int* __restrict__ tgt,
    const float* __restrict__ x, float* __restrict__ agg, float* __restrict__ deg) {
  int tid = blockIdx.x * blockDim.x + threadIdx.x;
  if (tid >= N_EDGES * 8) return;
  int e = tid >> 3, q = tid & 7;
  int s = src[e], t = tgt[e];
  float4 v = reinterpret_cast<const float4*>(x)[s * 8 + q];
  float* a = agg + t * 32 + q * 4;
  atomicAdd(a + 0, v.x);
  atomicAdd(a + 1, v.y);
  atomicAdd(a + 2, v.z);
  atomicAdd(a + 3, v.w);
  if (q == 0) atomicAdd(deg + t, 1.0f);
}

__global__ __launch_bounds__(256) void scatter2(
    const int* __restrict__ src, const int* __restrict__ tgt,
    const float* __restrict__ h, float* __restrict__ agg) {
  int tid = blockIdx.x * blockDim.x + threadIdx.x;
  if (tid >= N_EDGES * 16) return;
  int e = tid >> 4, q = tid & 15;
  int s = src[e], t = tgt[e];
  float4 v = reinterpret_cast<const float4*>(h)[s * 16 + q];
  float* a = agg + t * 64 + q * 4;
  atomicAdd(a + 0, v.x);
  atomicAdd(a + 1, v.y);
  atomicAdd(a + 2, v.z);
  atomicAdd(a + 3, v.w);
}

__global__ __launch_bounds__(256) void scatter3(
    const int* __restrict__ src, const int* __restrict__ tgt,
    const float* __restrict__ y, const float* __restrict__ invdeg,
    float* __restrict__ out) {
  int e = blockIdx.x * blockDim.x + threadIdx.x;
  if (e >= N_EDGES) return;
  int s = src[e], t = tgt[e];
  float2 v = reinterpret_cast<const float2*>(y)[s];
  float inv = invdeg[t];
  atomicAdd(out + t * 2 + 0, v.x * inv);
  atomicAdd(out + t * 2 + 1, v.y * inv);
}

template <int CIN, int LAYER1>
__global__ __launch_bounds__(256) void node_ln(
    const float* __restrict__ xin, const float* __restrict__ agg,
    float* __restrict__ deg, const float* __restrict__ Wl,
    const float* __restrict__ Wr, const float* __restrict__ b,
    const float* __restrict__ g, const float* __restrict__ be,
    float* __restrict__ hout) {
  int gid = blockIdx.x * blockDim.x + threadIdx.x;
  int node = gid >> 6;
  int c = threadIdx.x & 63;
  if (node >= N_NODES) return;

  float inv;
  if (LAYER1) {
    float dg = deg[node];
    inv = 1.0f / fmaxf(dg, 1.0f);
    if (c == 0) deg[node] = inv;
  } else {
    inv = deg[node];
  }

  const float* xr = xin + (size_t)node * CIN;
  const float* ar = agg + (size_t)node * CIN;
  float acc = b[c];
#pragma unroll
  for (int k = 0; k < CIN; k++) {
    acc = fmaf(ar[k] * inv, Wl[k * 64 + c], acc);
    acc = fmaf(xr[k], Wr[k * 64 + c], acc);
  }

  float s = acc;
#pragma unroll
  for (int off = 32; off; off >>= 1) s += __shfl_xor(s, off);
  float mu = s * (1.0f / 64.0f);
  float d = acc - mu;
  float v2 = d * d;
#pragma unroll
  for (int off = 32; off; off >>= 1) v2 += __shfl_xor(v2, off);
  float var = v2 * (1.0f / 64.0f);
  float o = d * rsqrtf(var + 1e-5f) * g[c] + be[c];
  hout[(size_t)node * 64 + c] = fmaxf(o, 0.0f);
}

// ==================== launch ====================

extern "C" void kernel_launch(void* const* d_in, const int* in_sizes, int n_in,
                              void* d_out, int out_size, void* d_ws, size_t ws_size,
                              hipStream_t stream) {
  const float* x = (const float*)d_in[0];
  const int* ei = (const int*)d_in[1];
  const int* src = ei;
  const int* tgt = ei + N_EDGES;
  const float* Wl1 = (const float*)d_in[2];
  const float* Wr1 = (const float*)d_in[3];
  const float* b1 = (const float*)d_in[4];
  const float* g1 = (const float*)d_in[5];
  const float* be1 = (const float*)d_in[6];
  const float* Wl2 = (const float*)d_in[7];
  const float* Wr2 = (const float*)d_in[8];
  const float* b2 = (const float*)d_in[9];
  const float* g2 = (const float*)d_in[10];
  const float* be2 = (const float*)d_in[11];
  const float* Wl3 = (const float*)d_in[12];
  const float* Wr3 = (const float*)d_in[13];
  const float* b3 = (const float*)d_in[14];
  float* out = (float*)d_out;
  char* ws = (char*)d_ws;

  // ---- CSR-path workspace layout ----
  size_t p = 0;
  auto carve = [&](size_t bytes) {
    size_t r = p;
    p += (bytes + 255) & ~(size_t)255;
    return r;
  };
  size_t count_off = carve((size_t)NBK * 4);
  size_t base_off = carve((size_t)(NBK + 1) * 4);
  size_t cursor_off = carve((size_t)NBK * 4);
  size_t offs_off = carve((size_t)N_NODES * 4);
  size_t csr_off = carve((size_t)N_EDGES * 4);
  size_t xh_off = carve((size_t)N_NODES * 32 * 2);   // x fp16; later y3 (800KB)
  size_t h1_off = carve((size_t)N_NODES * 64 * 2);   // h1 fp16
  size_t h2_off = carve((size_t)N_NODES * 64 * 4);   // h2 f32; binned aliases front
  size_t need_csr = p;

  const int NB = (N_NODES + 255) / 256;  // 391

  if (ws_size >= need_csr) {
    int* count = (int*)(ws + count_off);
    int* bktBase = (int*)(ws + base_off);
    int* cursor = (int*)(ws + cursor_off);
    int* offs = (int*)(ws + offs_off);
    int* csr = (int*)(ws + csr_off);
    __half2* xh = (__half2*)(ws + xh_off);
    __half* h1 = (__half*)(ws + h1_off);
    float* h2 = (float*)(ws + h2_off);
    unsigned int* binned = (unsigned int*)h2;  // 12.8MB, dead before h2 is written

    hipMemsetAsync(count, 0, (size_t)NBK * 4, stream);
    bin_hist<<<NBLK_BIN, 256, 0, stream>>>(tgt, count);
    bin_scan<<<1, 512, 0, stream>>>(count, bktBase, cursor);
    bin_scatter<<<NBLK_BIN, 256, 0, stream>>>(src, tgt, cursor, binned);
    bucket_sort<<<NBK, 256, 0, stream>>>(binned, bktBase, csr, offs);

    to_half2<<<(N_NODES * 16 + 255) / 256, 256, 0, stream>>>(x, xh, N_NODES * 16);

    layer1_fused<<<(N_NODES + 3) / 4, 256, 0, stream>>>(
        xh, csr, offs, Wl1, Wr1, b1, g1, be1, h1);
    layer2_fused<<<(N_NODES + 3) / 4, 256, 0, stream>>>(
        (const __half2*)h1, csr, offs, Wl2, Wr2, b2, g2, be2, h2);
    float* y3 = (float*)xh;  // xh dead; reuse (800KB)
    node3<<<NB, 256, 0, stream>>>(h2, Wl3, Wr3, b3, y3, out);
    gather3<<<(N_NODES + 3) / 4, 256, 0, stream>>>(y3, csr, offs, out);
  } else {
    // fallback: round-1 atomic path (needs ~51.7MB)
    float* deg = (float*)ws;
    float* A = (float*)(ws + (size_t)N_NODES * 4);
    float* B = A + (size_t)N_NODES * 64;

    hipMemsetAsync(deg, 0, (size_t)N_NODES * 4, stream);
    hipMemsetAsync(A, 0, (size_t)N_NODES * 32 * 4, stream);
    scatter1<<<(N_EDGES * 8 + 255) / 256, 256, 0, stream>>>(src, tgt, x, A, deg);
    node_ln<32, 1><<<(N_NODES * 64 + 255) / 256, 256, 0, stream>>>(
        x, A, deg, Wl1, Wr1, b1, g1, be1, B);
    hipMemsetAsync(A, 0, (size_t)N_NODES * 64 * 4, stream);
    scatter2<<<(N_EDGES * 16 + 255) / 256, 256, 0, stream>>>(src, tgt, B, A);
    node_ln<64, 0><<<(N_NODES * 64 + 255) / 256, 256, 0, stream>>>(
        B, A, deg, Wl2, Wr2, b2, g2, be2, B);
    float* y3 = A;
    node3<<<NB, 256, 0, stream>>>(B, Wl3, Wr3, b3, y3, out);
    scatter3<<<(N_EDGES + 255) / 256, 256, 0, stream>>>(src, tgt, y3, deg, out);
  }
}